// Round 14
// baseline (689.086 us; speedup 1.0000x reference)
//
#include <hip/hip_runtime.h>
#include <cstdint>

#define NN 20000
#define TT 256
#define EE 320000
#define GG 64
#define EMBD 768
#define FIND 512

typedef __bf16 bf16x8 __attribute__((ext_vector_type(8)));
typedef float f32x4 __attribute__((ext_vector_type(4)));

__device__ __forceinline__ float b2f(unsigned short u) {
  union { unsigned int i; float f; } v; v.i = ((unsigned int)u) << 16; return v.f;
}
__device__ __forceinline__ float b2f_lo(unsigned int u) {
  union { unsigned int i; float f; } v; v.i = u << 16; return v.f;
}
__device__ __forceinline__ float b2f_hi(unsigned int u) {
  union { unsigned int i; float f; } v; v.i = u & 0xFFFF0000u; return v.f;
}
__device__ __forceinline__ unsigned short f2bf(float f) {
  union { float f; unsigned int i; } v; v.f = f;
  unsigned int u = v.i;
  return (unsigned short)((u + 0x7FFFu + ((u >> 16) & 1u)) >> 16);
}
__device__ __forceinline__ unsigned int pack2bf(float lo, float hi) {
  return (unsigned int)f2bf(lo) | ((unsigned int)f2bf(hi) << 16);
}

// async global->LDS, 16B per lane. LDS dest is wave-uniform base + lane*16.
__device__ __forceinline__ void gload_lds16(const void* g, void* l) {
  auto gp = reinterpret_cast<const __attribute__((address_space(1))) char*>(
      reinterpret_cast<uintptr_t>(g));
  auto lp = reinterpret_cast<__attribute__((address_space(3))) char*>(
      (unsigned int)(reinterpret_cast<uintptr_t>(l)));
  __builtin_amdgcn_global_load_lds(gp, lp, 16, 0, 0);
}

// ---------------- fused conv + init ----------------------------------------
// Conv: PERMANENTLY FROZEN r1 structure (182-187 us nominal; five
// restructures all regressed). Init blocks: edge histogram + weight
// transposes + batch histogram (cnt) — memory-bound, free overlap.
__global__ __launch_bounds__(256, 3) void k_conv(
    const float* __restrict__ x,
    const float* __restrict__ w0, const float* __restrict__ g0,
    const float* __restrict__ be0, const float* __restrict__ mu0,
    const float* __restrict__ va0,
    const float* __restrict__ w1, const float* __restrict__ w2,
    const float* __restrict__ g2, const float* __restrict__ be2,
    const float* __restrict__ mu2, const float* __restrict__ va2,
    unsigned short* __restrict__ out,
    const int* __restrict__ ei, int* __restrict__ deg,
    const float* __restrict__ g1w1, const float* __restrict__ g1w2,
    const float* __restrict__ g2w1, const float* __restrict__ g2w2,
    unsigned short* __restrict__ w1T, unsigned short* __restrict__ w2T,
    unsigned short* __restrict__ w3T, unsigned short* __restrict__ w4T,
    const int* __restrict__ batch, int* __restrict__ cnt) {
  __shared__ float xs[4][288];        // idx = t + 16, t in [-16, 271]
  __shared__ float h0s[4][8][288];    // [node][ch][t + 12], t in [-12, 275]
  const int tid = threadIdx.x;

  if (blockIdx.x >= NN / 4) {
    // ---- init path (block-uniform branch) ----
    int b = blockIdx.x - NN / 4;
    if (b < 1250) {                   // edge-count: 1250*256 >= EE
      int e = b * 256 + tid;
      if (e < EE) atomicAdd(&deg[ei[EE + e]], 1);
    } else if (b < 1250 + 8448) {     // weight transposes
      int i = (b - 1250) * 256 + tid;
      if (i < 393216) {               // 768 x 512 (K=512)
        int nrow = i >> 9, k = i & 511;
        w1T[i] = f2bf(g1w1[(size_t)k * 768 + nrow]);
      } else {
        int j = i - 393216;
        int which = j / 589824;       // 0..2, 768 x 768 each
        int r = j - which * 589824;
        int nrow = r / 768, k = r - nrow * 768;
        const float* src = which == 0 ? g1w2 : (which == 1 ? g2w1 : g2w2);
        unsigned short* dst = which == 0 ? w2T : (which == 1 ? w3T : w4T);
        dst[r] = f2bf(src[(size_t)k * 768 + nrow]);
      }
    } else {                          // batch histogram -> cnt
      int i = (b - 1250 - 8448) * 256 + tid;
      if (i < NN) atomicAdd(&cnt[batch[i]], 1);
    }
    return;
  }

  // ---- conv path: EXACT r1 structure (do not touch) ----
  const int wv = tid >> 6;            // node slot within block
  const int l = tid & 63;             // lane; handles t = 4l .. 4l+3
  const int n = blockIdx.x * 4 + wv;

  // stage x + zero halos
  float4 xv4 = *(const float4*)(x + (size_t)n * TT + 4 * l);
  *(float4*)&xs[wv][16 + 4 * l] = xv4;
  float4 z4 = make_float4(0.f, 0.f, 0.f, 0.f);
  if (l < 4) *(float4*)&xs[wv][4 * l] = z4;
  else if (l < 8) *(float4*)&xs[wv][272 + 4 * (l - 4)] = z4;
  __syncthreads();

  // conv0 (k=33, 1->8): window floats [4l, 4l+35]
  float win[36];
  #pragma unroll
  for (int i = 0; i < 9; ++i)
    *(float4*)&win[4 * i] = *(const float4*)&xs[wv][4 * l + 4 * i];
  float c0[4][8];
  #pragma unroll
  for (int j = 0; j < 4; ++j)
    #pragma unroll
    for (int c = 0; c < 8; ++c) c0[j][c] = 0.f;
  #pragma unroll
  for (int w = 0; w < 33; ++w) {
    #pragma unroll
    for (int c = 0; c < 8; ++c) {
      float wt = w0[w * 8 + c];            // uniform -> s_load
      #pragma unroll
      for (int j = 0; j < 4; ++j) c0[j][c] += win[w + j] * wt;
    }
  }
  // bn0 + store to channel-major LDS
  #pragma unroll
  for (int c = 0; c < 8; ++c) {
    float s = g0[c] * rsqrtf(va0[c] + 1e-5f);
    float o = be0[c] - mu0[c] * s;
    float4 v;
    v.x = c0[0][c] * s + o; v.y = c0[1][c] * s + o;
    v.z = c0[2][c] * s + o; v.w = c0[3][c] * s + o;
    *(float4*)&h0s[wv][c][12 + 4 * l] = v;
  }
  // zero halos of h0 rows: idx [0,12) and [268,288)
  if (l < 3) {
    #pragma unroll
    for (int c = 0; c < 8; ++c) *(float4*)&h0s[wv][c][4 * l] = z4;
  } else if (l < 8) {
    #pragma unroll
    for (int c = 0; c < 8; ++c) *(float4*)&h0s[wv][c][268 + 4 * (l - 3)] = z4;
  }
  __syncthreads();

  // conv1 depthwise (k=21) + relu, then conv2 pointwise (8->16)
  float p[4][16];
  #pragma unroll
  for (int j = 0; j < 4; ++j)
    #pragma unroll
    for (int k = 0; k < 16; ++k) p[j][k] = 0.f;
  #pragma unroll
  for (int c = 0; c < 8; ++c) {
    float hw[28];  // floats [4l, 4l+27] = t' in [4l-12, 4l+15]
    #pragma unroll
    for (int i = 0; i < 7; ++i)
      *(float4*)&hw[4 * i] = *(const float4*)&h0s[wv][c][4 * l + 4 * i];
    float d[4];
    #pragma unroll
    for (int j = 0; j < 4; ++j) {
      float a = 0.f;
      #pragma unroll
      for (int w = 0; w < 21; ++w) a += hw[j + w + 2] * w1[w * 8 + c];
      d[j] = fmaxf(a, 0.f);
    }
    #pragma unroll
    for (int k = 0; k < 16; ++k) {
      float wt = w2[c * 16 + k];
      #pragma unroll
      for (int j = 0; j < 4; ++j) p[j][k] += d[j] * wt;
    }
  }
  // bn2 + relu + mean-pool over 8 t (4 in-thread + lane pair)
  #pragma unroll
  for (int k = 0; k < 16; ++k) {
    float s = g2[k] * rsqrtf(va2[k] + 1e-5f);
    float o = be2[k] - mu2[k] * s;
    float v = 0.f;
    #pragma unroll
    for (int j = 0; j < 4; ++j) v += fmaxf(p[j][k] * s + o, 0.f);
    v += __shfl_xor(v, 1);
    p[0][k] = v * 0.125f;
  }
  if ((l & 1) == 0) {
    int grp = l >> 1;  // pool group 0..31
    unsigned short* op = out + (size_t)n * FIND + grp * 16;
    #pragma unroll
    for (int q = 0; q < 4; ++q) {
      ushort4 v;
      v.x = f2bf(p[0][q * 4 + 0]); v.y = f2bf(p[0][q * 4 + 1]);
      v.z = f2bf(p[0][q * 4 + 2]); v.w = f2bf(p[0][q * 4 + 3]);
      *(ushort4*)(op + q * 4) = v;
    }
  }
}

// ---------------- scan: register-serial, 20 elems/thread, one block ---------
__global__ __launch_bounds__(1024) void k_scan(const int* __restrict__ deg,
                                               int* __restrict__ row_ptr,
                                               int* __restrict__ cursor) {
  __shared__ int wsums[16];
  const int tid = threadIdx.x, lane = tid & 63, wid = tid >> 6;
  const int base = tid * 20;
  int v[20];
  int s = 0;
  #pragma unroll
  for (int i = 0; i < 20; ++i) {
    int idx = base + i;
    int d = (idx < NN) ? deg[idx] : 0;
    v[i] = s;                // local exclusive prefix
    s += d;
  }
  int inc = s;
  #pragma unroll
  for (int off = 1; off < 64; off <<= 1) {
    int t = __shfl_up(inc, off);
    if (lane >= off) inc += t;
  }
  if (lane == 63) wsums[wid] = inc;
  __syncthreads();
  if (wid == 0) {
    int ws = (lane < 16) ? wsums[lane] : 0;
    #pragma unroll
    for (int off = 1; off < 16; off <<= 1) {
      int t = __shfl_up(ws, off);
      if (lane >= off) ws += t;
    }
    if (lane < 16) wsums[lane] = ws;   // inclusive wave-sum prefix
    if (lane == 15) row_ptr[NN] = ws;  // grand total
  }
  __syncthreads();
  int woff = (wid > 0) ? wsums[wid - 1] : 0;
  int texcl = woff + inc - s;
  #pragma unroll
  for (int i = 0; i < 20; ++i) {
    int idx = base + i;
    if (idx < NN) { int e = texcl + v[i]; row_ptr[idx] = e; cursor[idx] = e; }
  }
}

__global__ void k_scatter(const int* __restrict__ ei, int* __restrict__ cursor,
                          int* __restrict__ csr_src) {
  int e = blockIdx.x * 256 + threadIdx.x;
  if (e < EE) {
    int d = ei[EE + e];
    int pos = atomicAdd(&cursor[d], 1);
    csr_src[pos] = ei[e];
  }
}

// ---------------- aggregation: out[n] = h[n] + sum_{e in(n)} h[src[e]] ------
// 256-thread blocks, 4 nodes/block (wave per node), 16B loads, edge loop
// unrolled x4 (12 independent vmem in flight per wave).
template <int KK>
__global__ __launch_bounds__(256) void k_agg(const unsigned short* __restrict__ h,
                                             const int* __restrict__ rp,
                                             const int* __restrict__ csr,
                                             unsigned short* __restrict__ out) {
  const int node = blockIdx.x * 4 + (threadIdx.x >> 6);
  const int lane = threadIdx.x & 63;
  constexpr int NE = (KK == 512) ? 8 : 12;
  float acc[NE];
  {
    const char* hp = (const char*)(h + (size_t)node * KK);
    uint4 v = *(const uint4*)(hp + lane * 16);
    acc[0] = b2f_lo(v.x); acc[1] = b2f_hi(v.x);
    acc[2] = b2f_lo(v.y); acc[3] = b2f_hi(v.y);
    acc[4] = b2f_lo(v.z); acc[5] = b2f_hi(v.z);
    acc[6] = b2f_lo(v.w); acc[7] = b2f_hi(v.w);
    if (KK == 768) {
      uint2 w = *(const uint2*)(hp + 1024 + lane * 8);
      acc[8] = b2f_lo(w.x); acc[9] = b2f_hi(w.x);
      acc[10] = b2f_lo(w.y); acc[11] = b2f_hi(w.y);
    }
  }
  int s = rp[node], e = rp[node + 1];
  int i = s;
  for (; i + 4 <= e; i += 4) {
    const char* sp0 = (const char*)(h + (size_t)csr[i] * KK);
    const char* sp1 = (const char*)(h + (size_t)csr[i + 1] * KK);
    const char* sp2 = (const char*)(h + (size_t)csr[i + 2] * KK);
    const char* sp3 = (const char*)(h + (size_t)csr[i + 3] * KK);
    uint4 v0 = *(const uint4*)(sp0 + lane * 16);
    uint4 v1 = *(const uint4*)(sp1 + lane * 16);
    uint4 v2 = *(const uint4*)(sp2 + lane * 16);
    uint4 v3 = *(const uint4*)(sp3 + lane * 16);
    uint2 w0g, w1g, w2g, w3g;
    if (KK == 768) {
      w0g = *(const uint2*)(sp0 + 1024 + lane * 8);
      w1g = *(const uint2*)(sp1 + 1024 + lane * 8);
      w2g = *(const uint2*)(sp2 + 1024 + lane * 8);
      w3g = *(const uint2*)(sp3 + 1024 + lane * 8);
    }
    acc[0] += (b2f_lo(v0.x) + b2f_lo(v1.x)) + (b2f_lo(v2.x) + b2f_lo(v3.x));
    acc[1] += (b2f_hi(v0.x) + b2f_hi(v1.x)) + (b2f_hi(v2.x) + b2f_hi(v3.x));
    acc[2] += (b2f_lo(v0.y) + b2f_lo(v1.y)) + (b2f_lo(v2.y) + b2f_lo(v3.y));
    acc[3] += (b2f_hi(v0.y) + b2f_hi(v1.y)) + (b2f_hi(v2.y) + b2f_hi(v3.y));
    acc[4] += (b2f_lo(v0.z) + b2f_lo(v1.z)) + (b2f_lo(v2.z) + b2f_lo(v3.z));
    acc[5] += (b2f_hi(v0.z) + b2f_hi(v1.z)) + (b2f_hi(v2.z) + b2f_hi(v3.z));
    acc[6] += (b2f_lo(v0.w) + b2f_lo(v1.w)) + (b2f_lo(v2.w) + b2f_lo(v3.w));
    acc[7] += (b2f_hi(v0.w) + b2f_hi(v1.w)) + (b2f_hi(v2.w) + b2f_hi(v3.w));
    if (KK == 768) {
      acc[8]  += (b2f_lo(w0g.x) + b2f_lo(w1g.x)) + (b2f_lo(w2g.x) + b2f_lo(w3g.x));
      acc[9]  += (b2f_hi(w0g.x) + b2f_hi(w1g.x)) + (b2f_hi(w2g.x) + b2f_hi(w3g.x));
      acc[10] += (b2f_lo(w0g.y) + b2f_lo(w1g.y)) + (b2f_lo(w2g.y) + b2f_lo(w3g.y));
      acc[11] += (b2f_hi(w0g.y) + b2f_hi(w1g.y)) + (b2f_hi(w2g.y) + b2f_hi(w3g.y));
    }
  }
  for (; i < e; ++i) {
    const char* sp = (const char*)(h + (size_t)csr[i] * KK);
    uint4 v = *(const uint4*)(sp + lane * 16);
    acc[0] += b2f_lo(v.x); acc[1] += b2f_hi(v.x);
    acc[2] += b2f_lo(v.y); acc[3] += b2f_hi(v.y);
    acc[4] += b2f_lo(v.z); acc[5] += b2f_hi(v.z);
    acc[6] += b2f_lo(v.w); acc[7] += b2f_hi(v.w);
    if (KK == 768) {
      uint2 w = *(const uint2*)(sp + 1024 + lane * 8);
      acc[8] += b2f_lo(w.x); acc[9] += b2f_hi(w.x);
      acc[10] += b2f_lo(w.y); acc[11] += b2f_hi(w.y);
    }
  }
  char* op = (char*)(out + (size_t)node * KK);
  uint4 v;
  v.x = pack2bf(acc[0], acc[1]); v.y = pack2bf(acc[2], acc[3]);
  v.z = pack2bf(acc[4], acc[5]); v.w = pack2bf(acc[6], acc[7]);
  *(uint4*)(op + lane * 16) = v;
  if (KK == 768) {
    uint2 w;
    w.x = pack2bf(acc[8], acc[9]); w.y = pack2bf(acc[10], acc[11]);
    *(uint2*)(op + 1024 + lane * 8) = w;
  }
}

// ---------------- GEMM: C(M,Nn) = relu(A(M,K) @ Bt(Nn,K)^T + bias) ----------
// 128x256 tile, BK=64: A re-read only 3x (r13, A-locality). 64 MFMA per
// barrier pair per wave. LDS 48 KB, 2 blocks/CU; grid 3x157 = 471 <= 512.
__global__ __launch_bounds__(256, 2) void k_gemm(const unsigned short* __restrict__ A,
                                                 const unsigned short* __restrict__ Bt,
                                                 const float* __restrict__ bias,
                                                 unsigned short* __restrict__ C,
                                                 int M, int K, int Nn) {
  __shared__ __align__(16) unsigned short As[128 * 64];  // 8 tiles x 128 chunks x 16B
  __shared__ __align__(16) unsigned short Bs[256 * 64];  // 16 tiles x 128 chunks x 16B
  const int tid = threadIdx.x;
  const int wave = tid >> 6, lane = tid & 63;
  const int m0 = blockIdx.y * 128;
  const int n0 = blockIdx.x * 256;
  const int wr = wave & 1, wc = wave >> 1;

  f32x4 zero = {0.f, 0.f, 0.f, 0.f};
  f32x4 acc[4][8];
  #pragma unroll
  for (int mt = 0; mt < 4; ++mt)
    #pragma unroll
    for (int nt = 0; nt < 8; ++nt) acc[mt][nt] = zero;

  for (int k0 = 0; k0 < K; k0 += 64) {
    __syncthreads();
    #pragma unroll
    for (int j = 0; j < 4; ++j) {
      int chunk = j * 256 + tid;                 // 0..1023 (A: 8 tiles)
      int tile = chunk >> 7, c = chunk & 127;
      int row = tile * 16 + (c & 15);
      int koff = (c >> 4) * 8;
      int gm = m0 + row; if (gm >= M) gm = 0;    // clamp: data unused
      gload_lds16(A + (size_t)gm * K + k0 + koff, (char*)As + chunk * 16);
    }
    #pragma unroll
    for (int j = 0; j < 8; ++j) {
      int chunk = j * 256 + tid;                 // 0..2047 (B: 16 tiles)
      int tile = chunk >> 7, c = chunk & 127;
      int row = tile * 16 + (c & 15);
      int koff = (c >> 4) * 8;
      gload_lds16(Bt + (size_t)(n0 + row) * K + k0 + koff, (char*)Bs + chunk * 16);
    }
    __syncthreads();
    #pragma unroll
    for (int s = 0; s < 2; ++s) {
      bf16x8 af[4], bfr[8];
      #pragma unroll
      for (int mt = 0; mt < 4; ++mt)
        af[mt] = *(const bf16x8*)((const char*)As +
                                  (((wr * 4 + mt) * 128 + s * 64 + lane) * 16));
      #pragma unroll
      for (int nt = 0; nt < 8; ++nt)
        bfr[nt] = *(const bf16x8*)((const char*)Bs +
                                   (((wc * 8 + nt) * 128 + s * 64 + lane) * 16));
      #pragma unroll
      for (int mt = 0; mt < 4; ++mt)
        #pragma unroll
        for (int nt = 0; nt < 8; ++nt)
          acc[mt][nt] = __builtin_amdgcn_mfma_f32_16x16x32_bf16(af[mt], bfr[nt], acc[mt][nt], 0, 0, 0);
    }
  }

  const int q = lane >> 4, ccol = lane & 15;
  #pragma unroll
  for (int nt = 0; nt < 8; ++nt) {
    int n = n0 + wc * 128 + nt * 16 + ccol;
    float bv = bias[n];
    #pragma unroll
    for (int mt = 0; mt < 4; ++mt) {
      int mbase = m0 + wr * 64 + mt * 16 + q * 4;
      #pragma unroll
      for (int r = 0; r < 4; ++r) {
        int m = mbase + r;
        if (m < M) {
          float v = acc[mt][nt][r] + bv;
          v = v > 0.f ? v : 0.f;
          C[(size_t)m * Nn + n] = f2bf(v);
        }
      }
    }
  }
}

// ---------------- GEMM + fused graph-mean-pool (final GIN layer) ------------
// Same mainloop as k_gemm, but the epilogue computes relu(acc+bias) and
// reduces column sums per graph (wave's 64-row window, batch via shfl),
// atomically accumulating into sums[64][768]. h2 is never written.
__global__ __launch_bounds__(256, 2) void k_gemm_pool(
    const unsigned short* __restrict__ A, const unsigned short* __restrict__ Bt,
    const float* __restrict__ bias, const int* __restrict__ batch,
    float* __restrict__ sums, int M, int K, int Nn) {
  __shared__ __align__(16) unsigned short As[128 * 64];
  __shared__ __align__(16) unsigned short Bs[256 * 64];
  const int tid = threadIdx.x;
  const int wave = tid >> 6, lane = tid & 63;
  const int m0 = blockIdx.y * 128;
  const int n0 = blockIdx.x * 256;
  const int wr = wave & 1, wc = wave >> 1;

  f32x4 zero = {0.f, 0.f, 0.f, 0.f};
  f32x4 acc[4][8];
  #pragma unroll
  for (int mt = 0; mt < 4; ++mt)
    #pragma unroll
    for (int nt = 0; nt < 8; ++nt) acc[mt][nt] = zero;

  for (int k0 = 0; k0 < K; k0 += 64) {
    __syncthreads();
    #pragma unroll
    for (int j = 0; j < 4; ++j) {
      int chunk = j * 256 + tid;
      int tile = chunk >> 7, c = chunk & 127;
      int row = tile * 16 + (c & 15);
      int koff = (c >> 4) * 8;
      int gm = m0 + row; if (gm >= M) gm = 0;
      gload_lds16(A + (size_t)gm * K + k0 + koff, (char*)As + chunk * 16);
    }
    #pragma unroll
    for (int j = 0; j < 8; ++j) {
      int chunk = j * 256 + tid;
      int tile = chunk >> 7, c = chunk & 127;
      int row = tile * 16 + (c & 15);
      int koff = (c >> 4) * 8;
      gload_lds16(Bt + (size_t)(n0 + row) * K + k0 + koff, (char*)Bs + chunk * 16);
    }
    __syncthreads();
    #pragma unroll
    for (int s = 0; s < 2; ++s) {
      bf16x8 af[4], bfr[8];
      #pragma unroll
      for (int mt = 0; mt < 4; ++mt)
        af[mt] = *(const bf16x8*)((const char*)As +
                                  (((wr * 4 + mt) * 128 + s * 64 + lane) * 16));
      #pragma unroll
      for (int nt = 0; nt < 8; ++nt)
        bfr[nt] = *(const bf16x8*)((const char*)Bs +
                                   (((wc * 8 + nt) * 128 + s * 64 + lane) * 16));
      #pragma unroll
      for (int mt = 0; mt < 4; ++mt)
        #pragma unroll
        for (int nt = 0; nt < 8; ++nt)
          acc[mt][nt] = __builtin_amdgcn_mfma_f32_16x16x32_bf16(af[mt], bfr[nt], acc[mt][nt], 0, 0, 0);
    }
  }

  const int q = lane >> 4, ccol = lane & 15;
  // relu(acc + bias) in place
  #pragma unroll
  for (int nt = 0; nt < 8; ++nt) {
    float bv = bias[n0 + wc * 128 + nt * 16 + ccol];
    #pragma unroll
    for (int mt = 0; mt < 4; ++mt)
      #pragma unroll
      for (int r = 0; r < 4; ++r)
        acc[mt][nt][r] = fmaxf(acc[mt][nt][r] + bv, 0.f);
  }
  // per-wave 64-row window pooling
  const int row_lo = m0 + wr * 64;
  int brow = row_lo + lane;
  int bl = batch[brow < M ? brow : (M - 1)];
  int g_lo = __shfl(bl, 0);
  int g_hi = __shfl(bl, 63);
  int grows[16];
  #pragma unroll
  for (int mt = 0; mt < 4; ++mt)
    #pragma unroll
    for (int r = 0; r < 4; ++r) {
      int idx = mt * 16 + q * 4 + r;
      int row = row_lo + idx;
      grows[mt * 4 + r] = (row < M) ? __shfl(bl, idx) : -1;
    }
  for (int g = g_lo; g <= g_hi; ++g) {
    #pragma unroll
    for (int nt = 0; nt < 8; ++nt) {
      float s = 0.f;
      #pragma unroll
      for (int mt = 0; mt < 4; ++mt)
        #pragma unroll
        for (int r = 0; r < 4; ++r)
          s += (grows[mt * 4 + r] == g) ? acc[mt][nt][r] : 0.f;
      s += __shfl_xor(s, 16);
      s += __shfl_xor(s, 32);
      if (q == 0) {
        int n = n0 + wc * 128 + nt * 16 + ccol;
        atomicAdd(&sums[g * EMBD + n], s);
      }
    }
  }
}

// ---------------- pool phase 2: dense 768->4 + log_softmax ------------------
__global__ __launch_bounds__(64) void k_pool2(const float* __restrict__ sums,
                                              const int* __restrict__ cnt,
                                              const float* __restrict__ dw,
                                              const float* __restrict__ db,
                                              float* __restrict__ outp) {
  int g = blockIdx.x, lane = threadIdx.x;
  float inv = 1.f / fmaxf((float)cnt[g], 1.f);
  float po[4] = {0.f, 0.f, 0.f, 0.f};
  #pragma unroll
  for (int i = 0; i < 12; ++i) {
    int f = lane + i * 64;
    float pv = sums[g * EMBD + f] * inv;
    #pragma unroll
    for (int o = 0; o < 4; ++o) po[o] += pv * dw[f * 4 + o];
  }
  #pragma unroll
  for (int o = 0; o < 4; ++o) {
    #pragma unroll
    for (int s = 1; s < 64; s <<= 1) po[o] += __shfl_xor(po[o], s);
  }
  if (lane == 0) {
    float l[4], m = -1e30f;
    #pragma unroll
    for (int o = 0; o < 4; ++o) { l[o] = po[o] + db[o]; m = fmaxf(m, l[o]); }
    float sum = 0.f;
    #pragma unroll
    for (int o = 0; o < 4; ++o) sum += expf(l[o] - m);
    float lse = m + logf(sum);
    #pragma unroll
    for (int o = 0; o < 4; ++o) outp[g * 4 + o] = l[o] - lse;
  }
}

// ---------------- launch ----------------------------------------------------
extern "C" void kernel_launch(void* const* d_in, const int* in_sizes, int n_in,
                              void* d_out, int out_size, void* d_ws, size_t ws_size,
                              hipStream_t stream) {
  const float* x        = (const float*)d_in[0];
  const int*   ei       = (const int*)d_in[1];
  const int*   batch    = (const int*)d_in[2];
  const float* conv0_w  = (const float*)d_in[3];
  const float* bn0_g    = (const float*)d_in[4];
  const float* bn0_b    = (const float*)d_in[5];
  const float* bn0_m    = (const float*)d_in[6];
  const float* bn0_v    = (const float*)d_in[7];
  const float* conv1_w  = (const float*)d_in[8];
  const float* conv2_w  = (const float*)d_in[9];
  const float* bn2_g    = (const float*)d_in[10];
  const float* bn2_b    = (const float*)d_in[11];
  const float* bn2_m    = (const float*)d_in[12];
  const float* bn2_v    = (const float*)d_in[13];
  const float* g1w1 = (const float*)d_in[14];
  const float* g1b1 = (const float*)d_in[15];
  const float* g1w2 = (const float*)d_in[16];
  const float* g1b2 = (const float*)d_in[17];
  const float* g2w1 = (const float*)d_in[18];
  const float* g2b1 = (const float*)d_in[19];
  const float* g2w2 = (const float*)d_in[20];
  const float* g2b2 = (const float*)d_in[21];
  const float* dw   = (const float*)d_in[22];
  const float* db   = (const float*)d_in[23];

  char* base = (char*)d_ws;
  unsigned short* h0 = (unsigned short*)(base);
  unsigned short* a2 = (unsigned short*)(base);
  unsigned short* a1 = (unsigned short*)(base + 20480000ull);
  unsigned short* z  = (unsigned short*)(base + 40960000ull);
  unsigned short* h1 = (unsigned short*)(base + 71680000ull);
  size_t off = 102400000ull;
  unsigned short* w1T = (unsigned short*)(base + off); off += 786432ull;    // 768x512
  unsigned short* w2T = (unsigned short*)(base + off); off += 1179648ull;   // 768x768
  unsigned short* w3T = (unsigned short*)(base + off); off += 1179648ull;
  unsigned short* w4T = (unsigned short*)(base + off); off += 1179648ull;
  // deg, sums, cnt contiguous -> single memset
  int*   deg     = (int*)(base + off);   off += 80000ull;
  float* sums    = (float*)(base + off); off += 196608ull;   // 64*768 f32
  int*   cnt     = (int*)(base + off);   off += 256ull;
  int*   row_ptr = (int*)(base + off);   off += 80128ull;
  int*   cursor  = (int*)(base + off);   off += 80128ull;
  int*   csr_src = (int*)(base + off);   off += 1280000ull;

  hipMemsetAsync(deg, 0, 80000ull + 196608ull + 256ull, stream);

  // conv blocks [0,5000) + init blocks [5000,14777)
  k_conv<<<NN / 4 + 1250 + 8448 + 79, 256, 0, stream>>>(
      x, conv0_w, bn0_g, bn0_b, bn0_m, bn0_v,
      conv1_w, conv2_w, bn2_g, bn2_b, bn2_m, bn2_v, h0,
      ei, deg, g1w1, g1w2, g2w1, g2w2, w1T, w2T, w3T, w4T, batch, cnt);

  k_scan<<<1, 1024, 0, stream>>>(deg, row_ptr, cursor);
  k_scatter<<<(EE + 255) / 256, 256, 0, stream>>>(ei, cursor, csr_src);

  dim3 ggrid(3, 157);   // 128-row M-tiles x 256-col N-tiles

  // GIN1
  k_agg<512><<<NN / 4, 256, 0, stream>>>(h0, row_ptr, csr_src, a1);
  k_gemm<<<ggrid, 256, 0, stream>>>(a1, w1T, g1b1, z, NN, 512, 768);
  k_gemm<<<ggrid, 256, 0, stream>>>(z, w2T, g1b2, h1, NN, 768, 768);
  // GIN2
  k_agg<768><<<NN / 4, 256, 0, stream>>>(h1, row_ptr, csr_src, a2);
  k_gemm<<<ggrid, 256, 0, stream>>>(a2, w3T, g2b1, z, NN, 768, 768);
  // final GEMM with fused relu + graph-mean pooling (h2 never materialized)
  k_gemm_pool<<<ggrid, 256, 0, stream>>>(z, w4T, g2b2, batch, sums, NN, 768, 768);

  k_pool2<<<GG, 64, 0, stream>>>(sums, cnt, dw, db, (float*)d_out);
}

// Round 15
// 655.010 us; speedup vs baseline: 1.0520x; 1.0520x over previous
//
#include <hip/hip_runtime.h>
#include <cstdint>

#define NN 20000
#define TT 256
#define EE 320000
#define GG 64
#define EMBD 768
#define FIND 512

typedef __bf16 bf16x8 __attribute__((ext_vector_type(8)));
typedef float f32x4 __attribute__((ext_vector_type(4)));

__device__ __forceinline__ float b2f(unsigned short u) {
  union { unsigned int i; float f; } v; v.i = ((unsigned int)u) << 16; return v.f;
}
__device__ __forceinline__ float b2f_lo(unsigned int u) {
  union { unsigned int i; float f; } v; v.i = u << 16; return v.f;
}
__device__ __forceinline__ float b2f_hi(unsigned int u) {
  union { unsigned int i; float f; } v; v.i = u & 0xFFFF0000u; return v.f;
}
__device__ __forceinline__ unsigned short f2bf(float f) {
  union { float f; unsigned int i; } v; v.f = f;
  unsigned int u = v.i;
  return (unsigned short)((u + 0x7FFFu + ((u >> 16) & 1u)) >> 16);
}
__device__ __forceinline__ unsigned int pack2bf(float lo, float hi) {
  return (unsigned int)f2bf(lo) | ((unsigned int)f2bf(hi) << 16);
}

// async global->LDS, 16B per lane. LDS dest is wave-uniform base + lane*16.
__device__ __forceinline__ void gload_lds16(const void* g, void* l) {
  auto gp = reinterpret_cast<const __attribute__((address_space(1))) char*>(
      reinterpret_cast<uintptr_t>(g));
  auto lp = reinterpret_cast<__attribute__((address_space(3))) char*>(
      (unsigned int)(reinterpret_cast<uintptr_t>(l)));
  __builtin_amdgcn_global_load_lds(gp, lp, 16, 0, 0);
}

// ---------------- fused conv + init ----------------------------------------
// Conv: PERMANENTLY FROZEN r1 structure (182-187 us nominal; five
// restructures all regressed). Init blocks: edge histogram + weight
// transposes — memory-bound, free overlap with the VALU-bound conv blocks.
__global__ __launch_bounds__(256, 3) void k_conv(
    const float* __restrict__ x,
    const float* __restrict__ w0, const float* __restrict__ g0,
    const float* __restrict__ be0, const float* __restrict__ mu0,
    const float* __restrict__ va0,
    const float* __restrict__ w1, const float* __restrict__ w2,
    const float* __restrict__ g2, const float* __restrict__ be2,
    const float* __restrict__ mu2, const float* __restrict__ va2,
    unsigned short* __restrict__ out,
    const int* __restrict__ ei, int* __restrict__ deg,
    const float* __restrict__ g1w1, const float* __restrict__ g1w2,
    const float* __restrict__ g2w1, const float* __restrict__ g2w2,
    unsigned short* __restrict__ w1T, unsigned short* __restrict__ w2T,
    unsigned short* __restrict__ w3T, unsigned short* __restrict__ w4T) {
  __shared__ float xs[4][288];        // idx = t + 16, t in [-16, 271]
  __shared__ float h0s[4][8][288];    // [node][ch][t + 12], t in [-12, 275]
  const int tid = threadIdx.x;

  if (blockIdx.x >= NN / 4) {
    // ---- init path (block-uniform branch) ----
    int b = blockIdx.x - NN / 4;
    if (b < 1250) {                   // edge-count: 1250*256 >= EE
      int e = b * 256 + tid;
      if (e < EE) atomicAdd(&deg[ei[EE + e]], 1);
    } else {                          // weight transposes
      int i = (b - 1250) * 256 + tid;
      if (i < 393216) {               // 768 x 512 (K=512)
        int nrow = i >> 9, k = i & 511;
        w1T[i] = f2bf(g1w1[(size_t)k * 768 + nrow]);
      } else {
        int j = i - 393216;
        int which = j / 589824;       // 0..2, 768 x 768 each
        int r = j - which * 589824;
        int nrow = r / 768, k = r - nrow * 768;
        const float* src = which == 0 ? g1w2 : (which == 1 ? g2w1 : g2w2);
        unsigned short* dst = which == 0 ? w2T : (which == 1 ? w3T : w4T);
        dst[r] = f2bf(src[(size_t)k * 768 + nrow]);
      }
    }
    return;
  }

  // ---- conv path: EXACT r1 structure (do not touch) ----
  const int wv = tid >> 6;            // node slot within block
  const int l = tid & 63;             // lane; handles t = 4l .. 4l+3
  const int n = blockIdx.x * 4 + wv;

  // stage x + zero halos
  float4 xv4 = *(const float4*)(x + (size_t)n * TT + 4 * l);
  *(float4*)&xs[wv][16 + 4 * l] = xv4;
  float4 z4 = make_float4(0.f, 0.f, 0.f, 0.f);
  if (l < 4) *(float4*)&xs[wv][4 * l] = z4;
  else if (l < 8) *(float4*)&xs[wv][272 + 4 * (l - 4)] = z4;
  __syncthreads();

  // conv0 (k=33, 1->8): window floats [4l, 4l+35]
  float win[36];
  #pragma unroll
  for (int i = 0; i < 9; ++i)
    *(float4*)&win[4 * i] = *(const float4*)&xs[wv][4 * l + 4 * i];
  float c0[4][8];
  #pragma unroll
  for (int j = 0; j < 4; ++j)
    #pragma unroll
    for (int c = 0; c < 8; ++c) c0[j][c] = 0.f;
  #pragma unroll
  for (int w = 0; w < 33; ++w) {
    #pragma unroll
    for (int c = 0; c < 8; ++c) {
      float wt = w0[w * 8 + c];            // uniform -> s_load
      #pragma unroll
      for (int j = 0; j < 4; ++j) c0[j][c] += win[w + j] * wt;
    }
  }
  // bn0 + store to channel-major LDS
  #pragma unroll
  for (int c = 0; c < 8; ++c) {
    float s = g0[c] * rsqrtf(va0[c] + 1e-5f);
    float o = be0[c] - mu0[c] * s;
    float4 v;
    v.x = c0[0][c] * s + o; v.y = c0[1][c] * s + o;
    v.z = c0[2][c] * s + o; v.w = c0[3][c] * s + o;
    *(float4*)&h0s[wv][c][12 + 4 * l] = v;
  }
  // zero halos of h0 rows: idx [0,12) and [268,288)
  if (l < 3) {
    #pragma unroll
    for (int c = 0; c < 8; ++c) *(float4*)&h0s[wv][c][4 * l] = z4;
  } else if (l < 8) {
    #pragma unroll
    for (int c = 0; c < 8; ++c) *(float4*)&h0s[wv][c][268 + 4 * (l - 3)] = z4;
  }
  __syncthreads();

  // conv1 depthwise (k=21) + relu, then conv2 pointwise (8->16)
  float p[4][16];
  #pragma unroll
  for (int j = 0; j < 4; ++j)
    #pragma unroll
    for (int k = 0; k < 16; ++k) p[j][k] = 0.f;
  #pragma unroll
  for (int c = 0; c < 8; ++c) {
    float hw[28];  // floats [4l, 4l+27] = t' in [4l-12, 4l+15]
    #pragma unroll
    for (int i = 0; i < 7; ++i)
      *(float4*)&hw[4 * i] = *(const float4*)&h0s[wv][c][4 * l + 4 * i];
    float d[4];
    #pragma unroll
    for (int j = 0; j < 4; ++j) {
      float a = 0.f;
      #pragma unroll
      for (int w = 0; w < 21; ++w) a += hw[j + w + 2] * w1[w * 8 + c];
      d[j] = fmaxf(a, 0.f);
    }
    #pragma unroll
    for (int k = 0; k < 16; ++k) {
      float wt = w2[c * 16 + k];
      #pragma unroll
      for (int j = 0; j < 4; ++j) p[j][k] += d[j] * wt;
    }
  }
  // bn2 + relu + mean-pool over 8 t (4 in-thread + lane pair)
  #pragma unroll
  for (int k = 0; k < 16; ++k) {
    float s = g2[k] * rsqrtf(va2[k] + 1e-5f);
    float o = be2[k] - mu2[k] * s;
    float v = 0.f;
    #pragma unroll
    for (int j = 0; j < 4; ++j) v += fmaxf(p[j][k] * s + o, 0.f);
    v += __shfl_xor(v, 1);
    p[0][k] = v * 0.125f;
  }
  if ((l & 1) == 0) {
    int grp = l >> 1;  // pool group 0..31
    unsigned short* op = out + (size_t)n * FIND + grp * 16;
    #pragma unroll
    for (int q = 0; q < 4; ++q) {
      ushort4 v;
      v.x = f2bf(p[0][q * 4 + 0]); v.y = f2bf(p[0][q * 4 + 1]);
      v.z = f2bf(p[0][q * 4 + 2]); v.w = f2bf(p[0][q * 4 + 3]);
      *(ushort4*)(op + q * 4) = v;
    }
  }
}

// ---------------- scan: register-serial, 20 elems/thread, one block ---------
__global__ __launch_bounds__(1024) void k_scan(const int* __restrict__ deg,
                                               int* __restrict__ row_ptr,
                                               int* __restrict__ cursor) {
  __shared__ int wsums[16];
  const int tid = threadIdx.x, lane = tid & 63, wid = tid >> 6;
  const int base = tid * 20;
  int v[20];
  int s = 0;
  #pragma unroll
  for (int i = 0; i < 20; ++i) {
    int idx = base + i;
    int d = (idx < NN) ? deg[idx] : 0;
    v[i] = s;                // local exclusive prefix
    s += d;
  }
  int inc = s;
  #pragma unroll
  for (int off = 1; off < 64; off <<= 1) {
    int t = __shfl_up(inc, off);
    if (lane >= off) inc += t;
  }
  if (lane == 63) wsums[wid] = inc;
  __syncthreads();
  if (wid == 0) {
    int ws = (lane < 16) ? wsums[lane] : 0;
    #pragma unroll
    for (int off = 1; off < 16; off <<= 1) {
      int t = __shfl_up(ws, off);
      if (lane >= off) ws += t;
    }
    if (lane < 16) wsums[lane] = ws;   // inclusive wave-sum prefix
    if (lane == 15) row_ptr[NN] = ws;  // grand total
  }
  __syncthreads();
  int woff = (wid > 0) ? wsums[wid - 1] : 0;
  int texcl = woff + inc - s;
  #pragma unroll
  for (int i = 0; i < 20; ++i) {
    int idx = base + i;
    if (idx < NN) { int e = texcl + v[i]; row_ptr[idx] = e; cursor[idx] = e; }
  }
}

__global__ void k_scatter(const int* __restrict__ ei, int* __restrict__ cursor,
                          int* __restrict__ csr_src) {
  int e = blockIdx.x * 256 + threadIdx.x;
  if (e < EE) {
    int d = ei[EE + e];
    int pos = atomicAdd(&cursor[d], 1);
    csr_src[pos] = ei[e];
  }
}

// ---------------- aggregation: out[n] = h[n] + sum_{e in(n)} h[src[e]] ------
// 256-thread blocks, 4 nodes/block (wave per node), 16B loads, edge loop
// unrolled x4 (12 independent vmem in flight per wave).
template <int KK>
__global__ __launch_bounds__(256) void k_agg(const unsigned short* __restrict__ h,
                                             const int* __restrict__ rp,
                                             const int* __restrict__ csr,
                                             unsigned short* __restrict__ out) {
  const int node = blockIdx.x * 4 + (threadIdx.x >> 6);
  const int lane = threadIdx.x & 63;
  constexpr int NE = (KK == 512) ? 8 : 12;
  float acc[NE];
  {
    const char* hp = (const char*)(h + (size_t)node * KK);
    uint4 v = *(const uint4*)(hp + lane * 16);
    acc[0] = b2f_lo(v.x); acc[1] = b2f_hi(v.x);
    acc[2] = b2f_lo(v.y); acc[3] = b2f_hi(v.y);
    acc[4] = b2f_lo(v.z); acc[5] = b2f_hi(v.z);
    acc[6] = b2f_lo(v.w); acc[7] = b2f_hi(v.w);
    if (KK == 768) {
      uint2 w = *(const uint2*)(hp + 1024 + lane * 8);
      acc[8] = b2f_lo(w.x); acc[9] = b2f_hi(w.x);
      acc[10] = b2f_lo(w.y); acc[11] = b2f_hi(w.y);
    }
  }
  int s = rp[node], e = rp[node + 1];
  int i = s;
  for (; i + 4 <= e; i += 4) {
    const char* sp0 = (const char*)(h + (size_t)csr[i] * KK);
    const char* sp1 = (const char*)(h + (size_t)csr[i + 1] * KK);
    const char* sp2 = (const char*)(h + (size_t)csr[i + 2] * KK);
    const char* sp3 = (const char*)(h + (size_t)csr[i + 3] * KK);
    uint4 v0 = *(const uint4*)(sp0 + lane * 16);
    uint4 v1 = *(const uint4*)(sp1 + lane * 16);
    uint4 v2 = *(const uint4*)(sp2 + lane * 16);
    uint4 v3 = *(const uint4*)(sp3 + lane * 16);
    uint2 w0g, w1g, w2g, w3g;
    if (KK == 768) {
      w0g = *(const uint2*)(sp0 + 1024 + lane * 8);
      w1g = *(const uint2*)(sp1 + 1024 + lane * 8);
      w2g = *(const uint2*)(sp2 + 1024 + lane * 8);
      w3g = *(const uint2*)(sp3 + 1024 + lane * 8);
    }
    acc[0] += (b2f_lo(v0.x) + b2f_lo(v1.x)) + (b2f_lo(v2.x) + b2f_lo(v3.x));
    acc[1] += (b2f_hi(v0.x) + b2f_hi(v1.x)) + (b2f_hi(v2.x) + b2f_hi(v3.x));
    acc[2] += (b2f_lo(v0.y) + b2f_lo(v1.y)) + (b2f_lo(v2.y) + b2f_lo(v3.y));
    acc[3] += (b2f_hi(v0.y) + b2f_hi(v1.y)) + (b2f_hi(v2.y) + b2f_hi(v3.y));
    acc[4] += (b2f_lo(v0.z) + b2f_lo(v1.z)) + (b2f_lo(v2.z) + b2f_lo(v3.z));
    acc[5] += (b2f_hi(v0.z) + b2f_hi(v1.z)) + (b2f_hi(v2.z) + b2f_hi(v3.z));
    acc[6] += (b2f_lo(v0.w) + b2f_lo(v1.w)) + (b2f_lo(v2.w) + b2f_lo(v3.w));
    acc[7] += (b2f_hi(v0.w) + b2f_hi(v1.w)) + (b2f_hi(v2.w) + b2f_hi(v3.w));
    if (KK == 768) {
      acc[8]  += (b2f_lo(w0g.x) + b2f_lo(w1g.x)) + (b2f_lo(w2g.x) + b2f_lo(w3g.x));
      acc[9]  += (b2f_hi(w0g.x) + b2f_hi(w1g.x)) + (b2f_hi(w2g.x) + b2f_hi(w3g.x));
      acc[10] += (b2f_lo(w0g.y) + b2f_lo(w1g.y)) + (b2f_lo(w2g.y) + b2f_lo(w3g.y));
      acc[11] += (b2f_hi(w0g.y) + b2f_hi(w1g.y)) + (b2f_hi(w2g.y) + b2f_hi(w3g.y));
    }
  }
  for (; i < e; ++i) {
    const char* sp = (const char*)(h + (size_t)csr[i] * KK);
    uint4 v = *(const uint4*)(sp + lane * 16);
    acc[0] += b2f_lo(v.x); acc[1] += b2f_hi(v.x);
    acc[2] += b2f_lo(v.y); acc[3] += b2f_hi(v.y);
    acc[4] += b2f_lo(v.z); acc[5] += b2f_hi(v.z);
    acc[6] += b2f_lo(v.w); acc[7] += b2f_hi(v.w);
    if (KK == 768) {
      uint2 w = *(const uint2*)(sp + 1024 + lane * 8);
      acc[8] += b2f_lo(w.x); acc[9] += b2f_hi(w.x);
      acc[10] += b2f_lo(w.y); acc[11] += b2f_hi(w.y);
    }
  }
  char* op = (char*)(out + (size_t)node * KK);
  uint4 v;
  v.x = pack2bf(acc[0], acc[1]); v.y = pack2bf(acc[2], acc[3]);
  v.z = pack2bf(acc[4], acc[5]); v.w = pack2bf(acc[6], acc[7]);
  *(uint4*)(op + lane * 16) = v;
  if (KK == 768) {
    uint2 w;
    w.x = pack2bf(acc[8], acc[9]); w.y = pack2bf(acc[10], acc[11]);
    *(uint2*)(op + 1024 + lane * 8) = w;
  }
}

// ---------------- GEMM: C(M,Nn) = relu(A(M,K) @ Bt(Nn,K)^T + bias) ----------
// 128x256 tile, BK=64, A-locality (3 N-tiles). XCD-aware 1D swizzle: the 3
// blocks sharing an A M-tile get linear IDs differing by 8 so round-robin
// dispatch puts them on the SAME XCD -> A M-tile re-reads hit that XCD's L2
// (36 TB/s) instead of LLC. 480 blocks (9 idle), 2 blocks/CU, co-resident.
__global__ __launch_bounds__(256, 2) void k_gemm(const unsigned short* __restrict__ A,
                                                 const unsigned short* __restrict__ Bt,
                                                 const float* __restrict__ bias,
                                                 unsigned short* __restrict__ C,
                                                 int M, int K, int Nn) {
  __shared__ __align__(16) unsigned short As[128 * 64];  // 8 tiles x 128 chunks x 16B
  __shared__ __align__(16) unsigned short Bs[256 * 64];  // 16 tiles x 128 chunks x 16B
  // swizzled work mapping
  const int id = blockIdx.x;
  const int xg = id & 7;              // xcd slot under round-robin
  const int kk = id >> 3;             // 0..59
  const int ntile = kk % 3;
  const int m_tile = (kk / 3) * 8 + xg;   // 0..159
  if (m_tile >= 157) return;
  const int m0 = m_tile * 128;
  const int n0 = ntile * 256;

  const int tid = threadIdx.x;
  const int wave = tid >> 6, lane = tid & 63;
  const int wr = wave & 1, wc = wave >> 1;

  f32x4 zero = {0.f, 0.f, 0.f, 0.f};
  f32x4 acc[4][8];
  #pragma unroll
  for (int mt = 0; mt < 4; ++mt)
    #pragma unroll
    for (int nt = 0; nt < 8; ++nt) acc[mt][nt] = zero;

  for (int k0 = 0; k0 < K; k0 += 64) {
    __syncthreads();
    #pragma unroll
    for (int j = 0; j < 4; ++j) {
      int chunk = j * 256 + tid;                 // 0..1023 (A: 8 tiles)
      int tile = chunk >> 7, c = chunk & 127;
      int row = tile * 16 + (c & 15);
      int koff = (c >> 4) * 8;
      int gm = m0 + row; if (gm >= M) gm = 0;    // clamp: data unused
      gload_lds16(A + (size_t)gm * K + k0 + koff, (char*)As + chunk * 16);
    }
    #pragma unroll
    for (int j = 0; j < 8; ++j) {
      int chunk = j * 256 + tid;                 // 0..2047 (B: 16 tiles)
      int tile = chunk >> 7, c = chunk & 127;
      int row = tile * 16 + (c & 15);
      int koff = (c >> 4) * 8;
      gload_lds16(Bt + (size_t)(n0 + row) * K + k0 + koff, (char*)Bs + chunk * 16);
    }
    __syncthreads();
    #pragma unroll
    for (int s = 0; s < 2; ++s) {
      bf16x8 af[4], bfr[8];
      #pragma unroll
      for (int mt = 0; mt < 4; ++mt)
        af[mt] = *(const bf16x8*)((const char*)As +
                                  (((wr * 4 + mt) * 128 + s * 64 + lane) * 16));
      #pragma unroll
      for (int nt = 0; nt < 8; ++nt)
        bfr[nt] = *(const bf16x8*)((const char*)Bs +
                                   (((wc * 8 + nt) * 128 + s * 64 + lane) * 16));
      #pragma unroll
      for (int mt = 0; mt < 4; ++mt)
        #pragma unroll
        for (int nt = 0; nt < 8; ++nt)
          acc[mt][nt] = __builtin_amdgcn_mfma_f32_16x16x32_bf16(af[mt], bfr[nt], acc[mt][nt], 0, 0, 0);
    }
  }

  const int q = lane >> 4, ccol = lane & 15;
  #pragma unroll
  for (int nt = 0; nt < 8; ++nt) {
    int n = n0 + wc * 128 + nt * 16 + ccol;
    float bv = bias[n];
    #pragma unroll
    for (int mt = 0; mt < 4; ++mt) {
      int mbase = m0 + wr * 64 + mt * 16 + q * 4;
      #pragma unroll
      for (int r = 0; r < 4; ++r) {
        int m = mbase + r;
        if (m < M) {
          float v = acc[mt][nt][r] + bv;
          v = v > 0.f ? v : 0.f;
          C[(size_t)m * Nn + n] = f2bf(v);
        }
      }
    }
  }
}

// ---------------- pool phase 1: per-graph sums (grid-wide, sorted batch) ----
// 32 nodes/block (625 blocks).
__global__ __launch_bounds__(256) void k_pool1(const unsigned short* __restrict__ h,
                                               const int* __restrict__ batch,
                                               float* __restrict__ sums,
                                               int* __restrict__ cnt) {
  const int tid = threadIdx.x;
  const int n0 = blockIdx.x * 32;
  const int n1 = min(n0 + 32, NN);
  int curg = batch[n0];
  float a0 = 0.f, a1 = 0.f, a2 = 0.f;
  int c = 0;
  for (int n = n0; n < n1; ++n) {
    int g = batch[n];  // uniform across block
    if (g != curg) {
      atomicAdd(&sums[curg * EMBD + tid], a0);
      atomicAdd(&sums[curg * EMBD + tid + 256], a1);
      atomicAdd(&sums[curg * EMBD + tid + 512], a2);
      if (tid == 0) atomicAdd(&cnt[curg], c);
      a0 = a1 = a2 = 0.f; c = 0; curg = g;
    }
    const unsigned short* hp = h + (size_t)n * EMBD;
    a0 += b2f(hp[tid]); a1 += b2f(hp[tid + 256]); a2 += b2f(hp[tid + 512]);
    ++c;
  }
  atomicAdd(&sums[curg * EMBD + tid], a0);
  atomicAdd(&sums[curg * EMBD + tid + 256], a1);
  atomicAdd(&sums[curg * EMBD + tid + 512], a2);
  if (tid == 0) atomicAdd(&cnt[curg], c);
}

// ---------------- pool phase 2: dense 768->4 + log_softmax ------------------
__global__ __launch_bounds__(64) void k_pool2(const float* __restrict__ sums,
                                              const int* __restrict__ cnt,
                                              const float* __restrict__ dw,
                                              const float* __restrict__ db,
                                              float* __restrict__ outp) {
  int g = blockIdx.x, lane = threadIdx.x;
  float inv = 1.f / fmaxf((float)cnt[g], 1.f);
  float po[4] = {0.f, 0.f, 0.f, 0.f};
  #pragma unroll
  for (int i = 0; i < 12; ++i) {
    int f = lane + i * 64;
    float pv = sums[g * EMBD + f] * inv;
    #pragma unroll
    for (int o = 0; o < 4; ++o) po[o] += pv * dw[f * 4 + o];
  }
  #pragma unroll
  for (int o = 0; o < 4; ++o) {
    #pragma unroll
    for (int s = 1; s < 64; s <<= 1) po[o] += __shfl_xor(po[o], s);
  }
  if (lane == 0) {
    float l[4], m = -1e30f;
    #pragma unroll
    for (int o = 0; o < 4; ++o) { l[o] = po[o] + db[o]; m = fmaxf(m, l[o]); }
    float sum = 0.f;
    #pragma unroll
    for (int o = 0; o < 4; ++o) sum += expf(l[o] - m);
    float lse = m + logf(sum);
    #pragma unroll
    for (int o = 0; o < 4; ++o) outp[g * 4 + o] = l[o] - lse;
  }
}

// ---------------- launch ----------------------------------------------------
extern "C" void kernel_launch(void* const* d_in, const int* in_sizes, int n_in,
                              void* d_out, int out_size, void* d_ws, size_t ws_size,
                              hipStream_t stream) {
  const float* x        = (const float*)d_in[0];
  const int*   ei       = (const int*)d_in[1];
  const int*   batch    = (const int*)d_in[2];
  const float* conv0_w  = (const float*)d_in[3];
  const float* bn0_g    = (const float*)d_in[4];
  const float* bn0_b    = (const float*)d_in[5];
  const float* bn0_m    = (const float*)d_in[6];
  const float* bn0_v    = (const float*)d_in[7];
  const float* conv1_w  = (const float*)d_in[8];
  const float* conv2_w  = (const float*)d_in[9];
  const float* bn2_g    = (const float*)d_in[10];
  const float* bn2_b    = (const float*)d_in[11];
  const float* bn2_m    = (const float*)d_in[12];
  const float* bn2_v    = (const float*)d_in[13];
  const float* g1w1 = (const float*)d_in[14];
  const float* g1b1 = (const float*)d_in[15];
  const float* g1w2 = (const float*)d_in[16];
  const float* g1b2 = (const float*)d_in[17];
  const float* g2w1 = (const float*)d_in[18];
  const float* g2b1 = (const float*)d_in[19];
  const float* g2w2 = (const float*)d_in[20];
  const float* g2b2 = (const float*)d_in[21];
  const float* dw   = (const float*)d_in[22];
  const float* db   = (const float*)d_in[23];

  char* base = (char*)d_ws;
  unsigned short* h0 = (unsigned short*)(base);
  unsigned short* a2 = (unsigned short*)(base);
  unsigned short* a1 = (unsigned short*)(base + 20480000ull);
  unsigned short* z  = (unsigned short*)(base + 40960000ull);
  unsigned short* h1 = (unsigned short*)(base + 71680000ull);
  unsigned short* h2 = h1;
  size_t off = 102400000ull;
  unsigned short* w1T = (unsigned short*)(base + off); off += 786432ull;    // 768x512
  unsigned short* w2T = (unsigned short*)(base + off); off += 1179648ull;   // 768x768
  unsigned short* w3T = (unsigned short*)(base + off); off += 1179648ull;
  unsigned short* w4T = (unsigned short*)(base + off); off += 1179648ull;
  // deg, sums, cnt contiguous -> single memset
  int*   deg     = (int*)(base + off);   off += 80000ull;
  float* sums    = (float*)(base + off); off += 196608ull;   // 64*768 f32
  int*   cnt     = (int*)(base + off);   off += 256ull;
  int*   row_ptr = (int*)(base + off);   off += 80128ull;
  int*   cursor  = (int*)(base + off);   off += 80128ull;
  int*   csr_src = (int*)(base + off);   off += 1280000ull;

  hipMemsetAsync(deg, 0, 80000ull + 196608ull + 256ull, stream);

  // conv blocks [0,5000) + init blocks [5000,14698)
  k_conv<<<NN / 4 + 1250 + 8448, 256, 0, stream>>>(
      x, conv0_w, bn0_g, bn0_b, bn0_m, bn0_v,
      conv1_w, conv2_w, bn2_g, bn2_b, bn2_m, bn2_v, h0,
      ei, deg, g1w1, g1w2, g2w1, g2w2, w1T, w2T, w3T, w4T);

  k_scan<<<1, 1024, 0, stream>>>(deg, row_ptr, cursor);
  k_scatter<<<(EE + 255) / 256, 256, 0, stream>>>(ei, cursor, csr_src);

  // GIN1
  k_agg<512><<<NN / 4, 256, 0, stream>>>(h0, row_ptr, csr_src, a1);
  k_gemm<<<480, 256, 0, stream>>>(a1, w1T, g1b1, z, NN, 512, 768);
  k_gemm<<<480, 256, 0, stream>>>(z, w2T, g1b2, h1, NN, 768, 768);
  // GIN2
  k_agg<768><<<NN / 4, 256, 0, stream>>>(h1, row_ptr, csr_src, a2);
  k_gemm<<<480, 256, 0, stream>>>(a2, w3T, g2b1, z, NN, 768, 768);
  k_gemm<<<480, 256, 0, stream>>>(z, w4T, g2b2, h2, NN, 768, 768);

  k_pool1<<<(NN + 31) / 32, 256, 0, stream>>>(h2, batch, sums, cnt);
  k_pool2<<<GG, 64, 0, stream>>>(sums, cnt, dw, db, (float*)d_out);
}